// Round 11
// baseline (52.760 us; speedup 1.0000x reference)
//
#include <hip/hip_runtime.h>

// Problem constants: B=2, L=8192, D=1024, f32 in/out.
#define BB 2
#define LL 8192
#define DD 1024
#define NC 128        // time chunks
#define TT 64         // chunk length (2^6)
#define NPAIR (DD/2)  // 512 d-pairs; one thread <-> one d-pair (8 B/lane)

// ph = exp(-(pr^2+pi^2)) * exp(i*atan2(pi,pr))
__device__ __forceinline__ void compute_ph(float pr, float pi, float& phr, float& phi) {
    float r2 = fmaf(pr, pr, pi * pi);
    float mag = expf(-r2);
    float r = sqrtf(r2);
    if (r > 1e-30f) {
        float inv = mag / r;
        phr = pr * inv;
        phi = pi * inv;
    } else {
        phr = mag;  // atan2(0,0)=0 -> phase 1+0i
        phi = 0.0f;
    }
}

// Pass 1: zero-init chunk end-state (read-only stream over x, float2 lanes).
__global__ __launch_bounds__(256) void k_partial(
    const float* __restrict__ x,
    const float* __restrict__ pr, const float* __restrict__ pi,
    const float* __restrict__ qr, const float* __restrict__ qi,
    float4* __restrict__ partial)
{
    const int p = blockIdx.x * 256 + threadIdx.x;   // d-pair 0..511
    const int j = blockIdx.y;
    const int b = blockIdx.z;
    const int d0 = 2 * p, d1 = d0 + 1;

    float phr0, phi0, phr1, phi1;
    compute_ph(pr[d0], pi[d0], phr0, phi0);
    compute_ph(pr[d1], pi[d1], phr1, phi1);
    const float q0r = qr[d0], q0i = qi[d0], q1r = qr[d1], q1i = qi[d1];

    const float2* xp = (const float2*)(x + ((size_t)b * LL + (size_t)j * TT) * DD) + p;

    float sr0 = 0.f, si0 = 0.f, sr1 = 0.f, si1 = 0.f;
    #pragma unroll 32
    for (int t = 0; t < TT; ++t) {
        float2 xv = xp[(size_t)t * NPAIR];
        float nr0 = fmaf(phr0, sr0, fmaf(-phi0, si0, q0r * xv.x));
        float ni0 = fmaf(phi0, sr0, fmaf(phr0, si0, q0i * xv.x));
        float nr1 = fmaf(phr1, sr1, fmaf(-phi1, si1, q1r * xv.y));
        float ni1 = fmaf(phi1, sr1, fmaf(phr1, si1, q1i * xv.y));
        sr0 = nr0; si0 = ni0; sr1 = nr1; si1 = ni1;
    }
    partial[((size_t)b * NC + j) * NPAIR + p] = make_float4(sr0, si0, sr1, si1);
}

// Pass 2 (tiny, throughput-shaped): prefix-scan partials -> per-chunk start
// states Sarr. 1024 threads; float4 lanes; 8-deep double-buffered prefetch.
#define SD 8
__global__ __launch_bounds__(256) void k_scan(
    const float* __restrict__ pr, const float* __restrict__ pi,
    const float* __restrict__ lr, const float* __restrict__ li,
    const float4* __restrict__ partial,
    float4* __restrict__ Sarr)
{
    const int idx = blockIdx.x * 256 + threadIdx.x;   // 0 .. BB*NPAIR-1
    const int p = idx & (NPAIR - 1);
    const int b = idx >> 9;                           // NPAIR = 2^9
    const int d0 = 2 * p, d1 = d0 + 1;

    float phr0, phi0, phr1, phi1;
    compute_ph(pr[d0], pi[d0], phr0, phi0);
    compute_ph(pr[d1], pi[d1], phr1, phi1);

    // a = ph^TT by repeated squaring (TT = 2^6)
    float a0r = phr0, a0i = phi0, a1r = phr1, a1i = phi1;
    #pragma unroll
    for (int k = 0; k < 6; ++k) {
        float n0r = a0r * a0r - a0i * a0i, n0i = 2.f * a0r * a0i;
        float n1r = a1r * a1r - a1i * a1i, n1i = 2.f * a1r * a1i;
        a0r = n0r; a0i = n0i; a1r = n1r; a1i = n1i;
    }

    float S0r = lr[d0], S0i = li[d0], S1r = lr[d1], S1i = li[d1];
    const float4* pb = partial + (size_t)b * NC * NPAIR + p;
    float4* sb = Sarr + (size_t)b * NC * NPAIR + p;

    float4 buf[SD];
    #pragma unroll
    for (int u = 0; u < SD; ++u) buf[u] = pb[(size_t)u * NPAIR];

    #pragma unroll
    for (int r = 0; r < NC / SD; ++r) {
        float4 nxt[SD];
        if (r < NC / SD - 1) {
            #pragma unroll
            for (int u = 0; u < SD; ++u)
                nxt[u] = pb[(size_t)((r + 1) * SD + u) * NPAIR];
        }
        #pragma unroll
        for (int u = 0; u < SD; ++u) {
            int j = r * SD + u;
            sb[(size_t)j * NPAIR] = make_float4(S0r, S0i, S1r, S1i);
            float n0r = fmaf(a0r, S0r, fmaf(-a0i, S0i, buf[u].x));
            float n0i = fmaf(a0i, S0r, fmaf(a0r, S0i, buf[u].y));
            float n1r = fmaf(a1r, S1r, fmaf(-a1i, S1i, buf[u].z));
            float n1i = fmaf(a1i, S1r, fmaf(a1r, S1i, buf[u].w));
            S0r = n0r; S0i = n0i; S1r = n1r; S1i = n1i;
        }
        if (r < NC / SD - 1) {
            #pragma unroll
            for (int u = 0; u < SD; ++u) buf[u] = nxt[u];
        }
    }
}

// Pass 3: pure stream — one Sarr load, then replay the chunk. No fold.
__global__ __launch_bounds__(256) void k_final(
    const float* __restrict__ x,
    const float* __restrict__ pr, const float* __restrict__ pi,
    const float* __restrict__ qr, const float* __restrict__ qi,
    const float4* __restrict__ Sarr,
    float* __restrict__ out)
{
    const int p = blockIdx.x * 256 + threadIdx.x;   // d-pair 0..511
    const int j = blockIdx.y;
    const int b = blockIdx.z;
    const int d0 = 2 * p, d1 = d0 + 1;

    float phr0, phi0, phr1, phi1;
    compute_ph(pr[d0], pi[d0], phr0, phi0);
    compute_ph(pr[d1], pi[d1], phr1, phi1);
    const float q0r = qr[d0], q0i = qi[d0], q1r = qr[d1], q1i = qi[d1];

    float4 S = Sarr[((size_t)b * NC + j) * NPAIR + p];
    float S0r = S.x, S0i = S.y, S1r = S.z, S1i = S.w;

    const size_t rowbase = (size_t)b * LL + (size_t)j * TT;
    const float2* xp = (const float2*)(x + rowbase * DD) + p;
    float2* op = (float2*)(out + rowbase * DD) + p;

    // load-32 / compute-32 / store-32 batches: deep MLP, few R/W turnarounds
    #pragma unroll
    for (int half = 0; half < 2; ++half) {
        float2 xv[32];
        #pragma unroll
        for (int u = 0; u < 32; ++u)
            xv[u] = xp[(size_t)(half * 32 + u) * NPAIR];
        float2 ov[32];
        #pragma unroll
        for (int u = 0; u < 32; ++u) {
            float n0r = fmaf(phr0, S0r, fmaf(-phi0, S0i, q0r * xv[u].x));
            float n0i = fmaf(phi0, S0r, fmaf(phr0, S0i, q0i * xv[u].x));
            float n1r = fmaf(phr1, S1r, fmaf(-phi1, S1i, q1r * xv[u].y));
            float n1i = fmaf(phi1, S1r, fmaf(phr1, S1i, q1i * xv[u].y));
            S0r = n0r; S0i = n0i; S1r = n1r; S1i = n1i;
            ov[u] = make_float2(n0r, n1r);
        }
        #pragma unroll
        for (int u = 0; u < 32; ++u)
            op[(size_t)(half * 32 + u) * NPAIR] = ov[u];
    }
}

extern "C" void kernel_launch(void* const* d_in, const int* in_sizes, int n_in,
                              void* d_out, int out_size, void* d_ws, size_t ws_size,
                              hipStream_t stream) {
    const float* x  = (const float*)d_in[0];
    const float* pr = (const float*)d_in[1];
    const float* pi = (const float*)d_in[2];
    const float* qr = (const float*)d_in[3];
    const float* qi = (const float*)d_in[4];
    const float* lr = (const float*)d_in[5];
    const float* li = (const float*)d_in[6];
    float* out = (float*)d_out;

    float4* partial = (float4*)d_ws;                     // BB*NC*NPAIR float4 = 2 MB
    float4* Sarr    = partial + (size_t)BB * NC * NPAIR; // 2 MB more

    dim3 grid(NPAIR / 256, NC, BB);    // 2 x 128 x 2 = 512 blocks
    k_partial<<<grid, 256, 0, stream>>>(x, pr, pi, qr, qi, partial);
    k_scan<<<(BB * NPAIR) / 256, 256, 0, stream>>>(pr, pi, lr, li, partial, Sarr);
    k_final<<<grid, 256, 0, stream>>>(x, pr, pi, qr, qi, Sarr, out);
}